// Round 3
// baseline (1415.325 us; speedup 1.0000x reference)
//
#include <hip/hip_runtime.h>
#include <cfloat>

#define LATENT 256
#define NV 8192
#define NROWS 16384   // B*H*W
#define HW 1024
#define CHW (LATENT * HW)         // 262144
#define PLANE 4194304             // B*C*H*W
#define IDX_OFF (2 * PLANE)       // 8388608
#define LOSS_OFF (IDX_OFF + NROWS)

#define RPB 256        // rows per block (16 waves x 16 rows)
#define RPW 16         // rows per wave (wave-uniform)
#define KSPLIT 2048    // codes per block (4 splits)
#define KPASS 128      // codes per pass (64 lanes x 2)
#define NPASS (KSPLIT / KPASS)   // 16
#define NINT (NPASS * 8)         // 128 staging intervals

typedef float f32x16 __attribute__((ext_vector_type(16)));
typedef float f32x4v __attribute__((ext_vector_type(4)));
typedef float f32x2v __attribute__((ext_vector_type(2)));

// ---------------- kernel 1: fused distance + argmin ----------------
// fp32 semantics identical to round-2 (passed, absmax 0): d = fp32(X - 2*dot),
// dot = c-ascending fp32 FMA chain, X = f64-accurate row norm, first-index ties.
// Wave owns 16 rows (A-operand wave-uniform -> scalar loads, SGPR FMA operand);
// lanes own 2 codes (B-operand: one ds_read_b64 per 32 FMAs -> VALU-bound).
__global__ __launch_bounds__(1024) void dist_argmin(
    const float* __restrict__ x, const float* __restrict__ ek,
    float* __restrict__ pval, int* __restrict__ pidx) {
  __shared__ float es[2][32][130];   // [buf][c][code], stride 130 (2 mod 32)
  __shared__ double Xpart[4][256];
  __shared__ float Xs[256];
  const int t = threadIdx.x;
  const int split = blockIdx.x & 3;   // XCD k sees only split k&3 -> ek L2-resident
  const int rowblk = blockIdx.x >> 2;
  const int i0 = rowblk << 8;
  const int b = i0 >> 10;
  const int hw0 = i0 & 1023;
  const float* xb = x + (size_t)b * CHW + hw0;

  // ---- row norms: 4 threads/row, f64 chunked (error ~1e-13 << 0.5 ulp fp32) ----
  {
    const int r = t & 255;
    const int part = t >> 8;  // 0..3
    const float* xp = xb + r + (size_t)(part * 64) * HW;
    double s = 0.0;
    for (int c = 0; c < 64; ++c) {
      double v = (double)xp[(size_t)c * HW];
      s = fma(v, v, s);
    }
    Xpart[part][r] = s;
  }
  __syncthreads();
  if (t < 256) {
    double s = ((Xpart[0][t] + Xpart[1][t]) + Xpart[2][t]) + Xpart[3][t];
    Xs[t] = (float)s;
  }
  __syncthreads();

  const int wv = __builtin_amdgcn_readfirstlane(t >> 6);  // uniform wave id
  const int lane = t & 63;
  const float* ap = xb + wv * RPW;  // uniform pointer: a[c][r] = ap[c*HW + r]
  float X[RPW];
  #pragma unroll
  for (int r = 0; r < RPW; ++r) X[r] = Xs[wv * RPW + r];

  float mval[RPW];
  int midx[RPW];
  #pragma unroll
  for (int r = 0; r < RPW; ++r) { mval[r] = FLT_MAX; midx[r] = 0; }

  const int kbase = split * KSPLIT;
  const int skl = t >> 3;        // staged code 0..127
  const int scl = (t & 7) << 2;  // staged c offset 0,4,..,28

  // prefetch interval 0 (pass 0, cc 0)
  f32x4v streg = *(const f32x4v*)(ek + (size_t)(kbase + skl) * LATENT + scl);

  for (int pass = 0; pass < NPASS; ++pass) {
    float acc[RPW][2];
    #pragma unroll
    for (int r = 0; r < RPW; ++r) { acc[r][0] = 0.f; acc[r][1] = 0.f; }
    for (int cc = 0; cc < 8; ++cc) {
      const int iv = pass * 8 + cc;
      const int buf = iv & 1;
      __syncthreads();  // readers of es[buf] (interval iv-2) are done
      #pragma unroll
      for (int i = 0; i < 4; ++i) es[buf][scl + i][skl] = streg[i];
      const int ni = iv + 1;
      if (ni < NINT) {  // issue next-interval global loads (hidden under compute)
        const int nk0 = kbase + (ni >> 3) * KPASS;
        const int ncc = ni & 7;
        streg = *(const f32x4v*)(ek + (size_t)(nk0 + skl) * LATENT + ncc * 32 + scl);
      }
      __syncthreads();  // es[buf] fully written
      const float* esb = &es[buf][0][0];
      #pragma unroll 8
      for (int ci = 0; ci < 32; ++ci) {
        f32x16 av = *(const f32x16*)(ap + (size_t)(cc * 32 + ci) * HW);
        f32x2v bv = *(const f32x2v*)(esb + ci * 130 + lane * 2);
        #pragma unroll
        for (int r = 0; r < RPW; ++r) {
          acc[r][0] = fmaf(av[r], bv[0], acc[r][0]);
          acc[r][1] = fmaf(av[r], bv[1], acc[r][1]);
        }
      }
    }
    const int k0 = kbase + pass * KPASS + lane * 2;
    #pragma unroll
    for (int r = 0; r < RPW; ++r) {
      float d0 = fmaf(-2.0f, acc[r][0], X[r]);
      float d1 = fmaf(-2.0f, acc[r][1], X[r]);
      if (d0 < mval[r]) { mval[r] = d0; midx[r] = k0; }      // strict <: first wins
      if (d1 < mval[r]) { mval[r] = d1; midx[r] = k0 + 1; }
    }
  }

  // ---- cross-lane argmin per row (smaller index on equal) ----
  float resv = 0.f;
  int resi = 0;
  #pragma unroll
  for (int r = 0; r < RPW; ++r) {
    float bvv = mval[r];
    int bii = midx[r];
    #pragma unroll
    for (int off = 1; off < 64; off <<= 1) {
      float ov = __shfl_xor(bvv, off, 64);
      int oi = __shfl_xor(bii, off, 64);
      if (ov < bvv || (ov == bvv && oi < bii)) { bvv = ov; bii = oi; }
    }
    if (lane == r) { resv = bvv; resi = bii; }
  }
  if (lane < RPW) {
    const int row = i0 + wv * RPW + lane;
    pval[row * 4 + split] = resv;
    pidx[row * 4 + split] = resi;
  }
}

// ---------------- kernel 2: merge idx, gather-GEMM, outputs ----------------
__global__ __launch_bounds__(256) void out_kernel(
    const float* __restrict__ ek, const float* __restrict__ ev,
    const float* __restrict__ x, const float* __restrict__ pval,
    const int* __restrict__ pidx, float* __restrict__ out,
    float* __restrict__ bsum) {
  __shared__ float As[32][68];    // gathered ek chunk, [c][row]
  __shared__ float Vs[32][260];   // V chunk, [c][j]
  __shared__ int idx_s[64];
  __shared__ float red[256];
  const int t = threadIdx.x;
  const int blk = blockIdx.x;
  const int i0 = blk << 6;
  if (t < 64) {
    int i = i0 + t;
    float bv = pval[i * 4];
    int bi = pidx[i * 4];
    #pragma unroll
    for (int s = 1; s < 4; ++s) {
      float v = pval[i * 4 + s];
      int ii = pidx[i * 4 + s];
      if (v < bv || (v == bv && ii < bi)) { bv = v; bi = ii; }
    }
    idx_s[t] = bi;
    out[IDX_OFF + i] = (float)bi;
  }
  const int ty = t >> 5;  // rows ty*8 (of 64)
  const int tx = t & 31;  // j = tx*8 (of 256)
  float acc[8][8];
  #pragma unroll
  for (int r = 0; r < 8; ++r)
    #pragma unroll
    for (int j = 0; j < 8; ++j) acc[r][j] = 0.f;
  for (int cc = 0; cc < 8; ++cc) {
    __syncthreads();
    {  // gather A chunk: 64 rows x 32 c, transposed
      int r = t >> 2, cl = (t & 3) << 3;
      const float* eb = ek + (size_t)idx_s[r] * LATENT + (cc << 5) + cl;
      float4 v0 = *(const float4*)eb;
      float4 v1 = *(const float4*)(eb + 4);
      As[cl + 0][r] = v0.x; As[cl + 1][r] = v0.y;
      As[cl + 2][r] = v0.z; As[cl + 3][r] = v0.w;
      As[cl + 4][r] = v1.x; As[cl + 5][r] = v1.y;
      As[cl + 6][r] = v1.z; As[cl + 7][r] = v1.w;
    }
    {  // stage V chunk: 32 c x 256 j
      int c = t >> 3, jb = (t & 7) << 5;
      const float* vb = ev + (size_t)((cc << 5) + c) * LATENT + jb;
      float4* dst = (float4*)&Vs[c][jb];
      #pragma unroll
      for (int q = 0; q < 8; ++q) dst[q] = *(const float4*)(vb + 4 * q);
    }
    __syncthreads();
    #pragma unroll
    for (int c = 0; c < 32; ++c) {
      float a[8], bv[8];
      *(float4*)&a[0] = *(const float4*)&As[c][ty << 3];
      *(float4*)&a[4] = *(const float4*)&As[c][(ty << 3) + 4];
      *(float4*)&bv[0] = *(const float4*)&Vs[c][tx << 3];
      *(float4*)&bv[4] = *(const float4*)&Vs[c][(tx << 3) + 4];
      #pragma unroll
      for (int r = 0; r < 8; ++r)
        #pragma unroll
        for (int j = 0; j < 8; ++j) acc[r][j] = fmaf(a[r], bv[j], acc[r][j]);
    }
  }
  // epilogue: transpose to (b,c,h,w); xq_st = xt + (xq - xt); xq_grad = xq
  const int bb = i0 >> 10;
  const int rbase = (i0 & 1023) + (ty << 3);
  float lsum = 0.f;
  #pragma unroll
  for (int j = 0; j < 8; ++j) {
    int jc = (tx << 3) + j;
    const float* xp = x + (size_t)bb * CHW + (size_t)jc * HW + rbase;
    float* o0 = out + (size_t)bb * CHW + (size_t)jc * HW + rbase;
    float* o1 = o0 + PLANE;
    float st[8], xq0[8];
    #pragma unroll
    for (int r = 0; r < 8; ++r) {
      float xq = acc[r][j];
      float xt = xp[r];
      float tmp = xq - xt;
      lsum = fmaf(tmp, tmp, lsum);
      st[r] = xt + tmp;
      xq0[r] = xq;
    }
    *(float4*)(o0 + 0) = make_float4(st[0], st[1], st[2], st[3]);
    *(float4*)(o0 + 4) = make_float4(st[4], st[5], st[6], st[7]);
    *(float4*)(o1 + 0) = make_float4(xq0[0], xq0[1], xq0[2], xq0[3]);
    *(float4*)(o1 + 4) = make_float4(xq0[4], xq0[5], xq0[6], xq0[7]);
  }
  red[t] = lsum;
  __syncthreads();
  for (int s = 128; s > 0; s >>= 1) {
    if (t < s) red[t] += red[t + s];
    __syncthreads();
  }
  if (t == 0) bsum[blk] = red[0];
}

// ---------------- kernel 3: loss ----------------
__global__ __launch_bounds__(256) void fin_kernel(const float* __restrict__ bsum,
                                                  float* __restrict__ out) {
  __shared__ float red[256];
  int t = threadIdx.x;
  red[t] = bsum[t];
  __syncthreads();
  for (int s = 128; s > 0; s >>= 1) {
    if (t < s) red[t] += red[t + s];
    __syncthreads();
  }
  if (t == 0) {
    float m = red[0] / (float)PLANE;
    out[LOSS_OFF] = m + 0.25f * m;
  }
}

extern "C" void kernel_launch(void* const* d_in, const int* in_sizes, int n_in,
                              void* d_out, int out_size, void* d_ws, size_t ws_size,
                              hipStream_t stream) {
  const float* x = (const float*)d_in[0];
  const float* ek = (const float*)d_in[1];
  const float* ev = (const float*)d_in[2];
  float* out = (float*)d_out;
  float* ws = (float*)d_ws;
  float* pval = ws;                                // 4*NROWS floats
  int* pidx = (int*)(ws + 4 * NROWS);              // 4*NROWS ints
  float* bsum = ws + 8 * NROWS;                    // 256

  dist_argmin<<<256, 1024, 0, stream>>>(x, ek, pval, pidx);
  out_kernel<<<256, 256, 0, stream>>>(ek, ev, x, pval, pidx, out, bsum);
  fin_kernel<<<1, 256, 0, stream>>>(bsum, out);
}

// Round 4
// 584.790 us; speedup vs baseline: 2.4202x; 2.4202x over previous
//
#include <hip/hip_runtime.h>
#include <cfloat>

#define LATENT 256
#define NV 8192
#define NROWS 16384   // B*H*W
#define HW 1024
#define CHW (LATENT * HW)         // 262144
#define PLANE 4194304             // B*C*H*W
#define IDX_OFF (2 * PLANE)       // 8388608
#define LOSS_OFF (IDX_OFF + NROWS)
#define MARGIN_S 6e-4f            // >= worst-case 2*|S_chain-S_approx| + ulp terms (3.4e-4)

typedef __bf16 bf16x8 __attribute__((ext_vector_type(8)));
typedef float f32x4 __attribute__((ext_vector_type(4)));

__device__ inline unsigned short f2bf(float f) {  // RNE f32->bf16 (finite inputs)
  unsigned u = __builtin_bit_cast(unsigned, f);
  u = u + 0x7FFFu + ((u >> 16) & 1u);
  return (unsigned short)(u >> 16);
}
__device__ inline float bf2f(unsigned short h) {
  return __builtin_bit_cast(float, (unsigned)h << 16);
}

// ---------------- prep: ek -> ek_hi (bf16 [k][c]) + ekT (f32 [c][k]) ----------------
__global__ __launch_bounds__(256) void prep_ek(const float* __restrict__ ek,
                                               unsigned short* __restrict__ ek_hi,
                                               float* __restrict__ ekT) {
  __shared__ float tile[64][68];
  const int t = threadIdx.x;
  const int k0 = (blockIdx.x >> 2) << 6;
  const int c0 = (blockIdx.x & 3) << 6;
  #pragma unroll
  for (int p = 0; p < 4; ++p) {
    int id = (p << 8) + t;
    int r = id >> 4;             // code-local
    int c4 = (id & 15) << 2;     // c offset
    float4 v = *(const float4*)(ek + (size_t)(k0 + r) * LATENT + c0 + c4);
    *(float4*)&tile[r][c4] = v;
    ushort4 h;
    h.x = f2bf(v.x); h.y = f2bf(v.y); h.z = f2bf(v.z); h.w = f2bf(v.w);
    *(ushort4*)(ek_hi + (size_t)(k0 + r) * LATENT + c0 + c4) = h;
  }
  __syncthreads();
  #pragma unroll
  for (int p = 0; p < 4; ++p) {
    int id = (p << 8) + t;
    int rc = id >> 4;            // c-local
    int k4 = (id & 15) << 2;     // k offset
    float4 v = make_float4(tile[k4][rc], tile[k4 + 1][rc], tile[k4 + 2][rc], tile[k4 + 3][rc]);
    *(float4*)(ekT + (size_t)(c0 + rc) * NV + k0 + k4) = v;
  }
}

// ---------------- prep: x -> x_hi (bf16 [row][c], row = b*1024+hw) ----------------
__global__ __launch_bounds__(256) void prep_x(const float* __restrict__ x,
                                              unsigned short* __restrict__ x_hi) {
  __shared__ float tile[64][68];
  const int t = threadIdx.x;
  const int b = blockIdx.x >> 6;
  const int c0 = ((blockIdx.x >> 4) & 3) << 6;
  const int hw0 = (blockIdx.x & 15) << 6;
  #pragma unroll
  for (int p = 0; p < 4; ++p) {
    int id = (p << 8) + t;
    int r = id >> 4;            // c-local
    int h4 = (id & 15) << 2;    // hw offset
    float4 v = *(const float4*)(x + (size_t)b * CHW + (size_t)(c0 + r) * HW + hw0 + h4);
    *(float4*)&tile[r][h4] = v;
  }
  __syncthreads();
  #pragma unroll
  for (int p = 0; p < 4; ++p) {
    int id = (p << 8) + t;
    int rh = id >> 4;           // hw-local
    int c4 = (id & 15) << 2;    // c offset
    ushort4 h;
    h.x = f2bf(tile[c4][rh]);     h.y = f2bf(tile[c4 + 1][rh]);
    h.z = f2bf(tile[c4 + 2][rh]); h.w = f2bf(tile[c4 + 3][rh]);
    *(ushort4*)(x_hi + (size_t)((b << 10) + hw0 + rh) * LATENT + c0 + c4) = h;
  }
}

// ---------------- phase A: bf16 MFMA S=x.ek^T, per-(row,16-code-subtile) max ----------------
// Block: 256 codes x 256 rows, 8 waves (4m x 2n), each wave 64m x 128n.
// K-chunk 64, double-buffered LDS. m92-verified fragment pattern (row-major-K both operands).
__global__ __launch_bounds__(512) void phaseA(const unsigned short* __restrict__ ek_hi,
                                              const unsigned short* __restrict__ x_hi,
                                              unsigned short* __restrict__ smax16) {
  __shared__ unsigned short As[2][256][72];  // codes x k-chunk (pad 8: 2-way max on frag reads)
  __shared__ unsigned short Bs[2][256][72];  // rows  x k-chunk
  const int t = threadIdx.x;
  const int mt = blockIdx.x & 31;
  const int panel = blockIdx.x >> 5;
  const int m0 = mt << 8, r0 = panel << 8;
  const int sr = t & 255;
  const bool isB = t >= 256;
  const unsigned short* src = isB ? x_hi + (size_t)(r0 + sr) * LATENT
                                  : ek_hi + (size_t)(m0 + sr) * LATENT;
  uint4 reg[8];
  #pragma unroll
  for (int q = 0; q < 8; ++q) reg[q] = *(const uint4*)(src + (q << 3));
  #pragma unroll
  for (int q = 0; q < 8; ++q) {
    if (isB) *(uint4*)&Bs[0][sr][q << 3] = reg[q];
    else     *(uint4*)&As[0][sr][q << 3] = reg[q];
  }
  const int w = t >> 6, l = t & 63;
  const int lm = l & 15, lk = (l >> 4) << 3;
  const int mw = (w & 3) << 6;   // 0..192
  const int nw = (w >> 2) << 7;  // 0,128
  f32x4 acc[4][8];
  #pragma unroll
  for (int ms = 0; ms < 4; ++ms)
    #pragma unroll
    for (int ns = 0; ns < 8; ++ns) acc[ms][ns] = (f32x4){0.f, 0.f, 0.f, 0.f};
  for (int kc = 0; kc < 4; ++kc) {
    const int buf = kc & 1;
    if (kc < 3) {  // issue next-chunk loads early (latency hidden under MFMA)
      #pragma unroll
      for (int q = 0; q < 8; ++q)
        reg[q] = *(const uint4*)(src + ((kc + 1) << 6) + (q << 3));
    }
    __syncthreads();  // buf ready; prior readers of buf^1 done
    #pragma unroll
    for (int ks = 0; ks < 2; ++ks) {
      bf16x8 a[4], b[8];
      #pragma unroll
      for (int ms = 0; ms < 4; ++ms)
        a[ms] = *(const bf16x8*)&As[buf][mw + (ms << 4) + lm][(ks << 5) + lk];
      #pragma unroll
      for (int ns = 0; ns < 8; ++ns)
        b[ns] = *(const bf16x8*)&Bs[buf][nw + (ns << 4) + lm][(ks << 5) + lk];
      #pragma unroll
      for (int ms = 0; ms < 4; ++ms)
        #pragma unroll
        for (int ns = 0; ns < 8; ++ns)
          acc[ms][ns] = __builtin_amdgcn_mfma_f32_16x16x32_bf16(a[ms], b[ns], acc[ms][ns], 0, 0, 0);
    }
    if (kc < 3) {
      #pragma unroll
      for (int q = 0; q < 8; ++q) {
        if (isB) *(uint4*)&Bs[buf ^ 1][sr][q << 3] = reg[q];
        else     *(uint4*)&As[buf ^ 1][sr][q << 3] = reg[q];
      }
    }
  }
  // epilogue: per (16-code subtile, row): max of S_approx -> bf16
  // D layout (m89-verified): code m = base + (l>>4)*4 + reg, row n = base + (l&15)
  #pragma unroll
  for (int ms = 0; ms < 4; ++ms) {
    #pragma unroll
    for (int ns = 0; ns < 8; ++ns) {
      f32x4 v4 = acc[ms][ns];
      float v = fmaxf(fmaxf(v4[0], v4[1]), fmaxf(v4[2], v4[3]));
      v = fmaxf(v, __shfl_xor(v, 16, 64));
      v = fmaxf(v, __shfl_xor(v, 32, 64));
      if (l < 16) {
        int row_g = r0 + nw + (ns << 4) + l;
        int sidx = (mt << 4) + ((w & 3) << 2) + ms;
        smax16[(size_t)row_g * 512 + sidx] = f2bf(v);
      }
    }
  }
}

// ---------------- phase B: exact fp32-chain recompute over shortlist ----------------
// Wave per row. Identical numerics to the round-2-verified path:
// d = fmaf(-2, S_chain, X), S_chain = c-ascending fp32 FMA chain, X = f64 norm,
// first-index tie rule via lexicographic (d,k) min.
__global__ __launch_bounds__(256) void phaseB(const float* __restrict__ x,
                                              const float* __restrict__ ekT,
                                              const unsigned short* __restrict__ smax16,
                                              int* __restrict__ idxw,
                                              float* __restrict__ out) {
  __shared__ float xrow[4][256];
  const int t = threadIdx.x;
  const int w = t >> 6, l = t & 63;
  const int row = (blockIdx.x << 2) + w;
  const float* xb = x + (size_t)(row >> 10) * CHW + (row & 1023);
  double s = 0.0;
  #pragma unroll
  for (int q = 0; q < 4; ++q) {
    float v = xb[(size_t)((l << 2) + q) * HW];
    xrow[w][(l << 2) + q] = v;
    s = fma((double)v, (double)v, s);
  }
  #pragma unroll
  for (int off = 1; off < 64; off <<= 1) s += __shfl_xor(s, off, 64);
  const float X = (float)s;   // any fp32 in the binade: bucket structure invariant
  __syncthreads();            // xrow visible
  float vbf[8];
  #pragma unroll
  for (int p = 0; p < 8; ++p) vbf[p] = bf2f(smax16[(size_t)row * 512 + (p << 6) + l]);
  float smx = vbf[0];
  #pragma unroll
  for (int p = 1; p < 8; ++p) smx = fmaxf(smx, vbf[p]);
  #pragma unroll
  for (int off = 1; off < 64; off <<= 1) smx = fmaxf(smx, __shfl_xor(smx, off, 64));
  const float thr = smx - MARGIN_S;
  const float* xr = &xrow[w][0];
  float bd = FLT_MAX;
  int bk = 0x7fffffff;
  const int g = l >> 4;
  auto do_batch = [&](int T0, int T1, int T2, int T3) {
    int Tg = g == 0 ? T0 : g == 1 ? T1 : g == 2 ? T2 : T3;
    int k = (Tg << 4) + (l & 15);
    const float* ep = ekT + k;
    float f = 0.f;
    #pragma unroll 8
    for (int c = 0; c < 256; ++c) f = fmaf(xr[c], ep[(size_t)c << 13], f);
    float d = fmaf(-2.f, f, X);
    if (d < bd || (d == bd && k < bk)) { bd = d; bk = k; }
  };
  int p0 = 0, p1 = 0, p2 = 0, p3 = 0, np = 0;
  for (int p = 0; p < 8; ++p) {
    unsigned long long m = __ballot(vbf[p] >= thr);
    while (m) {
      int T = (p << 6) + __builtin_ctzll(m);
      m &= m - 1;
      if (np == 0) p0 = T; else if (np == 1) p1 = T; else if (np == 2) p2 = T; else p3 = T;
      ++np;
      if (np == 4) { do_batch(p0, p1, p2, p3); np = 0; }
    }
  }
  if (np > 0) {  // pad with p0 (duplicates cannot change the lexicographic min)
    if (np == 1) { p1 = p0; p2 = p0; p3 = p0; }
    else if (np == 2) { p2 = p0; p3 = p0; }
    else { p3 = p0; }
    do_batch(p0, p1, p2, p3);
  }
  #pragma unroll
  for (int off = 1; off < 64; off <<= 1) {
    float od = __shfl_xor(bd, off, 64);
    int ok = __shfl_xor(bk, off, 64);
    if (od < bd || (od == bd && ok < bk)) { bd = od; bk = ok; }
  }
  if (l == 0) {
    idxw[row] = bk;
    out[IDX_OFF + row] = (float)bk;
  }
}

// ---------------- out: gather-GEMM + transpose epilogue + loss partials ----------------
__global__ __launch_bounds__(256) void out_kernel(
    const float* __restrict__ ek, const float* __restrict__ ev,
    const float* __restrict__ x, const int* __restrict__ idxw,
    float* __restrict__ out, float* __restrict__ bsum) {
  __shared__ float As[32][68];    // gathered ek chunk, [c][row]
  __shared__ float Vs[32][260];   // V chunk, [c][j]
  __shared__ int idx_s[64];
  __shared__ float red[256];
  const int t = threadIdx.x;
  const int blk = blockIdx.x;
  const int i0 = blk << 6;
  if (t < 64) idx_s[t] = idxw[i0 + t];
  const int ty = t >> 5;  // rows ty*8 (of 64)
  const int tx = t & 31;  // j = tx*8 (of 256)
  float acc[8][8];
  #pragma unroll
  for (int r = 0; r < 8; ++r)
    #pragma unroll
    for (int j = 0; j < 8; ++j) acc[r][j] = 0.f;
  for (int cc = 0; cc < 8; ++cc) {
    __syncthreads();
    {  // gather A chunk: 64 rows x 32 c, transposed
      int r = t >> 2, cl = (t & 3) << 3;
      const float* eb = ek + (size_t)idx_s[r] * LATENT + (cc << 5) + cl;
      float4 v0 = *(const float4*)eb;
      float4 v1 = *(const float4*)(eb + 4);
      As[cl + 0][r] = v0.x; As[cl + 1][r] = v0.y;
      As[cl + 2][r] = v0.z; As[cl + 3][r] = v0.w;
      As[cl + 4][r] = v1.x; As[cl + 5][r] = v1.y;
      As[cl + 6][r] = v1.z; As[cl + 7][r] = v1.w;
    }
    {  // stage V chunk: 32 c x 256 j
      int c = t >> 3, jb = (t & 7) << 5;
      const float* vb = ev + (size_t)((cc << 5) + c) * LATENT + jb;
      float4* dst = (float4*)&Vs[c][jb];
      #pragma unroll
      for (int q = 0; q < 8; ++q) dst[q] = *(const float4*)(vb + 4 * q);
    }
    __syncthreads();
    #pragma unroll
    for (int c = 0; c < 32; ++c) {
      float a[8], bv[8];
      *(float4*)&a[0] = *(const float4*)&As[c][ty << 3];
      *(float4*)&a[4] = *(const float4*)&As[c][(ty << 3) + 4];
      *(float4*)&bv[0] = *(const float4*)&Vs[c][tx << 3];
      *(float4*)&bv[4] = *(const float4*)&Vs[c][(tx << 3) + 4];
      #pragma unroll
      for (int r = 0; r < 8; ++r)
        #pragma unroll
        for (int j = 0; j < 8; ++j) acc[r][j] = fmaf(a[r], bv[j], acc[r][j]);
    }
  }
  // epilogue: transpose to (b,c,h,w); xq_st = xt + (xq - xt); xq_grad = xq
  const int bb = i0 >> 10;
  const int rbase = (i0 & 1023) + (ty << 3);
  float lsum = 0.f;
  #pragma unroll
  for (int j = 0; j < 8; ++j) {
    int jc = (tx << 3) + j;
    const float* xp = x + (size_t)bb * CHW + (size_t)jc * HW + rbase;
    float* o0 = out + (size_t)bb * CHW + (size_t)jc * HW + rbase;
    float* o1 = o0 + PLANE;
    float st[8], xq0[8];
    #pragma unroll
    for (int r = 0; r < 8; ++r) {
      float xq = acc[r][j];
      float xt = xp[r];
      float tmp = xq - xt;
      lsum = fmaf(tmp, tmp, lsum);
      st[r] = xt + tmp;
      xq0[r] = xq;
    }
    *(float4*)(o0 + 0) = make_float4(st[0], st[1], st[2], st[3]);
    *(float4*)(o0 + 4) = make_float4(st[4], st[5], st[6], st[7]);
    *(float4*)(o1 + 0) = make_float4(xq0[0], xq0[1], xq0[2], xq0[3]);
    *(float4*)(o1 + 4) = make_float4(xq0[4], xq0[5], xq0[6], xq0[7]);
  }
  red[t] = lsum;
  __syncthreads();
  for (int s = 128; s > 0; s >>= 1) {
    if (t < s) red[t] += red[t + s];
    __syncthreads();
  }
  if (t == 0) bsum[blk] = red[0];
}

// ---------------- loss ----------------
__global__ __launch_bounds__(256) void fin_kernel(const float* __restrict__ bsum,
                                                  float* __restrict__ out) {
  __shared__ float red[256];
  int t = threadIdx.x;
  red[t] = bsum[t];
  __syncthreads();
  for (int s = 128; s > 0; s >>= 1) {
    if (t < s) red[t] += red[t + s];
    __syncthreads();
  }
  if (t == 0) {
    float m = red[0] / (float)PLANE;
    out[LOSS_OFF] = m + 0.25f * m;
  }
}

extern "C" void kernel_launch(void* const* d_in, const int* in_sizes, int n_in,
                              void* d_out, int out_size, void* d_ws, size_t ws_size,
                              hipStream_t stream) {
  const float* x = (const float*)d_in[0];
  const float* ek = (const float*)d_in[1];
  const float* ev = (const float*)d_in[2];
  float* out = (float*)d_out;
  char* base = (char*)d_ws;
  unsigned short* ek_hi  = (unsigned short*)(base);              //  4.0 MB
  unsigned short* x_hi   = (unsigned short*)(base + 4194304);    //  8.0 MB
  float*          ekT    = (float*)(base + 12582912);            //  8.0 MB
  unsigned short* smax16 = (unsigned short*)(base + 20971520);   // 16.0 MB
  int*            idxw   = (int*)(base + 37748736);              // 64 KB
  float*          bsum   = (float*)(base + 37814272);            //  1 KB

  prep_ek<<<512, 256, 0, stream>>>(ek, ek_hi, ekT);
  prep_x<<<1024, 256, 0, stream>>>(x, x_hi);
  phaseA<<<2048, 512, 0, stream>>>(ek_hi, x_hi, smax16);
  phaseB<<<4096, 256, 0, stream>>>(x, ekT, smax16, idxw, out);
  out_kernel<<<256, 256, 0, stream>>>(ek, ev, x, idxw, out, bsum);
  fin_kernel<<<1, 256, 0, stream>>>(bsum, out);
}